// Round 1
// baseline (464.516 us; speedup 1.0000x reference)
//
#include <hip/hip_runtime.h>
#include <math.h>

// Problem constants (from reference)
#define Bn 8
#define Hn 32
#define Dn 128
#define Cn 4096
#define PSn 128
#define NCHUNK 16
#define CHUNK 256   // positions per attention block (S=4096 / NCHUNK)

// -------------------- batch-8 GEMV: y[r][o] = dot(x[r,:], W[o,:]) + b[o] ----
// grid: o_total/16 blocks, 256 threads (4 waves). Each wave computes 4 output
// columns for all 8 batch rows. W reads: 64 lanes x float4 = 1 KB coalesced.
extern "C" __global__ __launch_bounds__(256) void gemv8(
    const float* __restrict__ xin, const float* __restrict__ W,
    const float* __restrict__ bias, float* __restrict__ y)
{
    const int wv   = threadIdx.x >> 6;
    const int lane = threadIdx.x & 63;
    const int o    = blockIdx.x * 16 + wv * 4;

    float acc0[8], acc1[8], acc2[8], acc3[8];
#pragma unroll
    for (int r = 0; r < 8; ++r) { acc0[r]=0.f; acc1[r]=0.f; acc2[r]=0.f; acc3[r]=0.f; }

    const float* wp = W + (size_t)o * Cn;
#pragma unroll 2
    for (int it = 0; it < Cn / 256; ++it) {
        const int c = it * 256 + lane * 4;
        const float4 w0 = *(const float4*)(wp + c);
        const float4 w1 = *(const float4*)(wp + Cn + c);
        const float4 w2 = *(const float4*)(wp + 2 * Cn + c);
        const float4 w3 = *(const float4*)(wp + 3 * Cn + c);
#pragma unroll
        for (int r = 0; r < 8; ++r) {
            const float4 xv = *(const float4*)(xin + r * Cn + c);
            acc0[r] = fmaf(w0.x,xv.x, fmaf(w0.y,xv.y, fmaf(w0.z,xv.z, fmaf(w0.w,xv.w, acc0[r]))));
            acc1[r] = fmaf(w1.x,xv.x, fmaf(w1.y,xv.y, fmaf(w1.z,xv.z, fmaf(w1.w,xv.w, acc1[r]))));
            acc2[r] = fmaf(w2.x,xv.x, fmaf(w2.y,xv.y, fmaf(w2.z,xv.z, fmaf(w2.w,xv.w, acc2[r]))));
            acc3[r] = fmaf(w3.x,xv.x, fmaf(w3.y,xv.y, fmaf(w3.z,xv.z, fmaf(w3.w,xv.w, acc3[r]))));
        }
    }
#pragma unroll
    for (int r = 0; r < 8; ++r) {
#pragma unroll
        for (int off = 32; off; off >>= 1) {
            acc0[r] += __shfl_xor(acc0[r], off);
            acc1[r] += __shfl_xor(acc1[r], off);
            acc2[r] += __shfl_xor(acc2[r], off);
            acc3[r] += __shfl_xor(acc3[r], off);
        }
    }
    if (lane == 0) {
        const float b0 = bias[o], b1 = bias[o+1], b2 = bias[o+2], b3 = bias[o+3];
#pragma unroll
        for (int r = 0; r < 8; ++r) {
            y[(size_t)r * Cn + o    ] = acc0[r] + b0;
            y[(size_t)r * Cn + o + 1] = acc1[r] + b1;
            y[(size_t)r * Cn + o + 2] = acc2[r] + b2;
            y[(size_t)r * Cn + o + 3] = acc3[r] + b3;
        }
    }
}

// -------------------- flash-decode partial attention ------------------------
// grid (NCHUNK, H, B), 256 threads. Phase 1: 8 groups of 32 lanes compute
// QK dots (coalesced 512B rows) + shuffle reduce. Phase 2: coalesced float4 V.
// Position s == cur_pos substitutes the freshly projected k/v (no cache write).
extern "C" __global__ __launch_bounds__(256) void attn_partial(
    const float* __restrict__ kp, const float* __restrict__ vp,
    const float* __restrict__ qn, const float* __restrict__ kn,
    const float* __restrict__ vn, const int* __restrict__ curp,
    float* __restrict__ pout, float* __restrict__ pml)
{
    const int chunk = blockIdx.x, h = blockIdx.y, b = blockIdx.z;
    const int tid = threadIdx.x;
    const int cur = *curp;

    __shared__ float  sc[CHUNK];
    __shared__ float  wred[8];
    __shared__ float4 red[8][32];

    const int l32 = tid & 31;
    const int g   = tid >> 5;           // 0..7
    const float4 q4   = *(const float4*)(qn + (size_t)b * Cn + h * Dn + l32 * 4);
    const float* newk = kn + (size_t)b * Cn + h * Dn;
    const float* newv = vn + (size_t)b * Cn + h * Dn;
    const int s0 = chunk * CHUNK;

    // Phase 1: scores
#pragma unroll 4
    for (int it = 0; it < CHUNK / 8; ++it) {
        const int sl = it * 8 + g;
        const int s  = s0 + sl;
        const float* krow;
        if (s == cur) krow = newk;
        else {
            const int pg = s >> 7, ps = s & 127;
            krow = kp + ((((size_t)pg * Bn + b) * Hn + h) * PSn + ps) * (size_t)Dn;
        }
        const float4 k4 = *(const float4*)(krow + l32 * 4);
        float d = fmaf(q4.x,k4.x, fmaf(q4.y,k4.y, fmaf(q4.z,k4.z, q4.w*k4.w)));
#pragma unroll
        for (int off = 16; off; off >>= 1) d += __shfl_xor(d, off);
        if (l32 == 0) sc[sl] = d * 0.08838834764831845f;  // 1/sqrt(128)
    }
    __syncthreads();

    // block softmax partial (m, l)
    float m = sc[tid];
#pragma unroll
    for (int off = 32; off; off >>= 1) m = fmaxf(m, __shfl_xor(m, off));
    if ((tid & 63) == 0) wred[tid >> 6] = m;
    __syncthreads();
    m = fmaxf(fmaxf(wred[0], wred[1]), fmaxf(wred[2], wred[3]));
    const float p = __expf(sc[tid] - m);
    sc[tid] = p;                     // own slot; cross-reads only after barrier
    float l = p;
#pragma unroll
    for (int off = 32; off; off >>= 1) l += __shfl_xor(l, off);
    if ((tid & 63) == 0) wred[4 + (tid >> 6)] = l;
    __syncthreads();
    const float lsum = wred[4] + wred[5] + wred[6] + wred[7];

    // Phase 2: out_partial[d] = sum_s p[s] * v[s,d]
    const int d4 = tid & 31;
    const int sg = tid >> 5;
    float4 acc = make_float4(0.f, 0.f, 0.f, 0.f);
    for (int it = 0; it < 32; ++it) {
        const int sl = it * 8 + sg;
        const int s  = s0 + sl;
        const float* vrow;
        if (s == cur) vrow = newv;
        else {
            const int pg = s >> 7, ps = s & 127;
            vrow = vp + ((((size_t)pg * Bn + b) * Hn + h) * PSn + ps) * (size_t)Dn;
        }
        const float4 v4 = *(const float4*)(vrow + d4 * 4);
        const float pw = sc[sl];
        acc.x = fmaf(pw, v4.x, acc.x);
        acc.y = fmaf(pw, v4.y, acc.y);
        acc.z = fmaf(pw, v4.z, acc.z);
        acc.w = fmaf(pw, v4.w, acc.w);
    }
    red[sg][d4] = acc;
    __syncthreads();
    const int head = b * Hn + h;
    if (tid < 32) {
        float4 o = make_float4(0.f, 0.f, 0.f, 0.f);
#pragma unroll
        for (int i = 0; i < 8; ++i) {
            const float4 t = red[i][tid];
            o.x += t.x; o.y += t.y; o.z += t.z; o.w += t.w;
        }
        float* dst = pout + ((size_t)(head * NCHUNK + chunk)) * Dn + tid * 4;
        *(float4*)dst = o;
    }
    if (tid == 0) {
        pml[(head * NCHUNK + chunk) * 2 + 0] = m;
        pml[(head * NCHUNK + chunk) * 2 + 1] = lsum;
    }
}

// -------------------- combine partials --------------------------------------
extern "C" __global__ __launch_bounds__(128) void attn_combine(
    const float* __restrict__ pout, const float* __restrict__ pml,
    float* __restrict__ aout)
{
    const int head = blockIdx.x;   // 0..255 = b*H + h
    const int tid  = threadIdx.x;  // 0..127 = d
    __shared__ float ml[NCHUNK * 2];
    if (tid < NCHUNK * 2) ml[tid] = pml[head * NCHUNK * 2 + tid];
    __syncthreads();
    float mstar = -1e30f;
#pragma unroll
    for (int i = 0; i < NCHUNK; ++i) mstar = fmaxf(mstar, ml[2 * i]);
    float L = 0.f, acc = 0.f;
#pragma unroll
    for (int i = 0; i < NCHUNK; ++i) {
        const float w = __expf(ml[2 * i] - mstar);
        L   += ml[2 * i + 1] * w;
        acc += w * pout[((size_t)head * NCHUNK + i) * Dn + tid];
    }
    aout[(size_t)head * Dn + tid] = acc / L;
}

// -------------------- launch -------------------------------------------------
extern "C" void kernel_launch(void* const* d_in, const int* in_sizes, int n_in,
                              void* d_out, int out_size, void* d_ws, size_t ws_size,
                              hipStream_t stream)
{
    const float* x  = (const float*)d_in[0];
    const float* kp = (const float*)d_in[1];
    const float* vp = (const float*)d_in[2];
    const float* Wq = (const float*)d_in[3];
    const float* bq = (const float*)d_in[4];
    const float* Wk = (const float*)d_in[5];
    const float* bk = (const float*)d_in[6];
    const float* Wv = (const float*)d_in[7];
    const float* bv = (const float*)d_in[8];
    const float* Wo = (const float*)d_in[9];
    const float* bo = (const float*)d_in[10];
    const int* curp = (const int*)d_in[11];

    // ws layout (floats): q | k_new | v_new | pout | pml | attn_out  (~2.6 MB)
    float* ws   = (float*)d_ws;
    float* q    = ws;               // 32768
    float* kn   = ws + 32768;       // 32768
    float* vn   = ws + 65536;       // 32768
    float* pout = ws + 98304;       // 256*16*128 = 524288
    float* pml  = ws + 622592;      // 256*16*2   = 8192
    float* aout = ws + 630784;      // 32768
    float* dout = (float*)d_out;

    gemv8<<<256, 256, 0, stream>>>(x, Wq, bq, q);
    gemv8<<<256, 256, 0, stream>>>(x, Wk, bk, kn);
    gemv8<<<256, 256, 0, stream>>>(x, Wv, bv, vn);
    attn_partial<<<dim3(NCHUNK, Hn, Bn), 256, 0, stream>>>(kp, vp, q, kn, vn, curp, pout, pml);
    attn_combine<<<256, 128, 0, stream>>>(pout, pml, aout);
    gemv8<<<256, 256, 0, stream>>>(aout, Wo, bo, dout);
}

// Round 2
// 350.534 us; speedup vs baseline: 1.3252x; 1.3252x over previous
//
#include <hip/hip_runtime.h>
#include <math.h>

// Problem constants (from reference)
#define Bn 8
#define Hn 32
#define Dn 128
#define Cn 4096
#define PSn 128
#define NCHUNK 16
#define CHUNK 256   // positions per attention block (S=4096 / NCHUNK)

// -------------------- batch-8 GEMV: y[r][o] = dot(x[r,:], W[o,:]) + b[o] ----
// 2 output columns per wave, 8 per block (256 thr) -> 512 blocks per matrix.
// gridDim.y selects the matrix (fused q/k/v projection); out stride 32768.
extern "C" __global__ __launch_bounds__(256) void gemv8(
    const float* __restrict__ xin,
    const float* __restrict__ W0, const float* __restrict__ b0,
    const float* __restrict__ W1, const float* __restrict__ b1,
    const float* __restrict__ W2, const float* __restrict__ b2,
    float* __restrict__ ybase)
{
    const int m    = blockIdx.y;
    const float* W    = (m == 0) ? W0 : ((m == 1) ? W1 : W2);
    const float* bias = (m == 0) ? b0 : ((m == 1) ? b1 : b2);
    float* y = ybase + (size_t)m * (Bn * Cn);

    const int wv   = threadIdx.x >> 6;
    const int lane = threadIdx.x & 63;
    const int o    = blockIdx.x * 8 + wv * 2;

    float acc0[8], acc1[8];
#pragma unroll
    for (int r = 0; r < 8; ++r) { acc0[r] = 0.f; acc1[r] = 0.f; }

    const float* wp = W + (size_t)o * Cn;
#pragma unroll 2
    for (int it = 0; it < Cn / 256; ++it) {
        const int c = it * 256 + lane * 4;
        const float4 w0 = *(const float4*)(wp + c);
        const float4 w1 = *(const float4*)(wp + Cn + c);
#pragma unroll
        for (int r = 0; r < 8; ++r) {
            const float4 xv = *(const float4*)(xin + r * Cn + c);
            acc0[r] = fmaf(w0.x,xv.x, fmaf(w0.y,xv.y, fmaf(w0.z,xv.z, fmaf(w0.w,xv.w, acc0[r]))));
            acc1[r] = fmaf(w1.x,xv.x, fmaf(w1.y,xv.y, fmaf(w1.z,xv.z, fmaf(w1.w,xv.w, acc1[r]))));
        }
    }
#pragma unroll
    for (int r = 0; r < 8; ++r) {
#pragma unroll
        for (int off = 32; off; off >>= 1) {
            acc0[r] += __shfl_xor(acc0[r], off);
            acc1[r] += __shfl_xor(acc1[r], off);
        }
    }
    if (lane == 0) {
        const float bb0 = bias[o], bb1 = bias[o + 1];
#pragma unroll
        for (int r = 0; r < 8; ++r) {
            float2 v = make_float2(acc0[r] + bb0, acc1[r] + bb1);
            *(float2*)(y + (size_t)r * Cn + o) = v;
        }
    }
}

// -------------------- flash-decode partial attention ------------------------
// grid (NCHUNK, H, B), 256 threads. Phase 1: 8 groups of 32 lanes compute
// QK dots (coalesced 512B rows) + shuffle reduce. Phase 2: coalesced float4 V.
// Position s == cur_pos substitutes the freshly projected k/v (no cache write).
extern "C" __global__ __launch_bounds__(256) void attn_partial(
    const float* __restrict__ kp, const float* __restrict__ vp,
    const float* __restrict__ qn, const float* __restrict__ kn,
    const float* __restrict__ vn, const int* __restrict__ curp,
    float* __restrict__ pout, float* __restrict__ pml)
{
    const int chunk = blockIdx.x, h = blockIdx.y, b = blockIdx.z;
    const int tid = threadIdx.x;
    const int cur = *curp;

    __shared__ float  sc[CHUNK];
    __shared__ float  wred[8];
    __shared__ float4 red[8][32];

    const int l32 = tid & 31;
    const int g   = tid >> 5;           // 0..7
    const float4 q4   = *(const float4*)(qn + (size_t)b * Cn + h * Dn + l32 * 4);
    const float* newk = kn + (size_t)b * Cn + h * Dn;
    const float* newv = vn + (size_t)b * Cn + h * Dn;
    const int s0 = chunk * CHUNK;

    // Phase 1: scores
#pragma unroll 4
    for (int it = 0; it < CHUNK / 8; ++it) {
        const int sl = it * 8 + g;
        const int s  = s0 + sl;
        const float* krow;
        if (s == cur) krow = newk;
        else {
            const int pg = s >> 7, ps = s & 127;
            krow = kp + ((((size_t)pg * Bn + b) * Hn + h) * PSn + ps) * (size_t)Dn;
        }
        const float4 k4 = *(const float4*)(krow + l32 * 4);
        float d = fmaf(q4.x,k4.x, fmaf(q4.y,k4.y, fmaf(q4.z,k4.z, q4.w*k4.w)));
#pragma unroll
        for (int off = 16; off; off >>= 1) d += __shfl_xor(d, off);
        if (l32 == 0) sc[sl] = d * 0.08838834764831845f;  // 1/sqrt(128)
    }
    __syncthreads();

    // block softmax partial (m, l)
    float m = sc[tid];
#pragma unroll
    for (int off = 32; off; off >>= 1) m = fmaxf(m, __shfl_xor(m, off));
    if ((tid & 63) == 0) wred[tid >> 6] = m;
    __syncthreads();
    m = fmaxf(fmaxf(wred[0], wred[1]), fmaxf(wred[2], wred[3]));
    const float p = __expf(sc[tid] - m);
    sc[tid] = p;                     // own slot; cross-reads only after barrier
    float l = p;
#pragma unroll
    for (int off = 32; off; off >>= 1) l += __shfl_xor(l, off);
    if ((tid & 63) == 0) wred[4 + (tid >> 6)] = l;
    __syncthreads();
    const float lsum = wred[4] + wred[5] + wred[6] + wred[7];

    // Phase 2: out_partial[d] = sum_s p[s] * v[s,d]
    const int d4 = tid & 31;
    const int sg = tid >> 5;
    float4 acc = make_float4(0.f, 0.f, 0.f, 0.f);
    for (int it = 0; it < 32; ++it) {
        const int sl = it * 8 + sg;
        const int s  = s0 + sl;
        const float* vrow;
        if (s == cur) vrow = newv;
        else {
            const int pg = s >> 7, ps = s & 127;
            vrow = vp + ((((size_t)pg * Bn + b) * Hn + h) * PSn + ps) * (size_t)Dn;
        }
        const float4 v4 = *(const float4*)(vrow + d4 * 4);
        const float pw = sc[sl];
        acc.x = fmaf(pw, v4.x, acc.x);
        acc.y = fmaf(pw, v4.y, acc.y);
        acc.z = fmaf(pw, v4.z, acc.z);
        acc.w = fmaf(pw, v4.w, acc.w);
    }
    red[sg][d4] = acc;
    __syncthreads();
    const int head = b * Hn + h;
    if (tid < 32) {
        float4 o = make_float4(0.f, 0.f, 0.f, 0.f);
#pragma unroll
        for (int i = 0; i < 8; ++i) {
            const float4 t = red[i][tid];
            o.x += t.x; o.y += t.y; o.z += t.z; o.w += t.w;
        }
        float* dst = pout + ((size_t)(head * NCHUNK + chunk)) * Dn + tid * 4;
        *(float4*)dst = o;
    }
    if (tid == 0) {
        pml[(head * NCHUNK + chunk) * 2 + 0] = m;
        pml[(head * NCHUNK + chunk) * 2 + 1] = lsum;
    }
}

// -------------------- combine partials --------------------------------------
extern "C" __global__ __launch_bounds__(128) void attn_combine(
    const float* __restrict__ pout, const float* __restrict__ pml,
    float* __restrict__ aout)
{
    const int head = blockIdx.x;   // 0..255 = b*H + h
    const int tid  = threadIdx.x;  // 0..127 = d
    __shared__ float ml[NCHUNK * 2];
    if (tid < NCHUNK * 2) ml[tid] = pml[head * NCHUNK * 2 + tid];
    __syncthreads();
    float mstar = -1e30f;
#pragma unroll
    for (int i = 0; i < NCHUNK; ++i) mstar = fmaxf(mstar, ml[2 * i]);
    float L = 0.f, acc = 0.f;
#pragma unroll
    for (int i = 0; i < NCHUNK; ++i) {
        const float w = __expf(ml[2 * i] - mstar);
        L   += ml[2 * i + 1] * w;
        acc += w * pout[((size_t)head * NCHUNK + i) * Dn + tid];
    }
    aout[(size_t)head * Dn + tid] = acc / L;
}

// -------------------- launch -------------------------------------------------
extern "C" void kernel_launch(void* const* d_in, const int* in_sizes, int n_in,
                              void* d_out, int out_size, void* d_ws, size_t ws_size,
                              hipStream_t stream)
{
    const float* x  = (const float*)d_in[0];
    const float* kp = (const float*)d_in[1];
    const float* vp = (const float*)d_in[2];
    const float* Wq = (const float*)d_in[3];
    const float* bq = (const float*)d_in[4];
    const float* Wk = (const float*)d_in[5];
    const float* bk = (const float*)d_in[6];
    const float* Wv = (const float*)d_in[7];
    const float* bv = (const float*)d_in[8];
    const float* Wo = (const float*)d_in[9];
    const float* bo = (const float*)d_in[10];
    const int* curp = (const int*)d_in[11];

    // ws layout (floats): q | k_new | v_new | pout | pml | attn_out  (~2.6 MB)
    float* ws   = (float*)d_ws;
    float* q    = ws;               // 32768
    float* kn   = ws + 32768;       // 32768
    float* vn   = ws + 65536;       // 32768
    float* pout = ws + 98304;       // 256*16*128 = 524288
    float* pml  = ws + 622592;      // 256*16*2   = 8192
    float* aout = ws + 630784;      // 32768
    float* dout = (float*)d_out;

    // Fused q/k/v projection: gridDim.y selects matrix; outputs q|kn|vn.
    gemv8<<<dim3(512, 3), 256, 0, stream>>>(x, Wq, bq, Wk, bk, Wv, bv, q);
    attn_partial<<<dim3(NCHUNK, Hn, Bn), 256, 0, stream>>>(kp, vp, q, kn, vn, curp, pout, pml);
    attn_combine<<<256, 128, 0, stream>>>(pout, pml, aout);
    // Output projection (single matrix -> gridDim.y == 1 uses slot 0).
    gemv8<<<dim3(512, 1), 256, 0, stream>>>(aout, Wo, bo, Wo, bo, Wo, bo, dout);
}

// Round 3
// 271.114 us; speedup vs baseline: 1.7134x; 1.2929x over previous
//
#include <hip/hip_runtime.h>
#include <math.h>

// Problem constants (from reference)
#define Bn 8
#define Hn 32
#define Dn 128
#define Cn 4096
#define PSn 128
#define NCHUNK 16
#define CHUNK 256   // positions per attention block (S=4096 / NCHUNK)

// -------------------- batch-8 GEMV, outer-product form ----------------------
// Block = 8 output cols x 8 batch rows. 4 waves; wave w owns c-quarter
// [w*1024, w*1024+1024). Each wave holds 64 accumulators (8r x 8o) and does
// an 8x8 outer product per float4 step: 16 loads + 256 fmaf per 256-float
// c-chunk, no duplicated x reads across waves. End: 6-step butterfly per acc,
// lane (r*8+o) keeps the sum, LDS cross-wave reduce, store.
// gridDim.y selects the matrix (fused q/k/v); y output stride Bn*Cn.
extern "C" __global__ __launch_bounds__(256) void gemv8(
    const float* __restrict__ xin,
    const float* __restrict__ W0, const float* __restrict__ b0,
    const float* __restrict__ W1, const float* __restrict__ b1,
    const float* __restrict__ W2, const float* __restrict__ b2,
    float* __restrict__ ybase)
{
    const int m    = blockIdx.y;
    const float* W    = (m == 0) ? W0 : ((m == 1) ? W1 : W2);
    const float* bias = (m == 0) ? b0 : ((m == 1) ? b1 : b2);
    float* y = ybase + (size_t)m * (Bn * Cn);

    const int wv   = threadIdx.x >> 6;   // wave 0..3 -> c-quarter
    const int lane = threadIdx.x & 63;
    const int obase = blockIdx.x * 8;

    float acc[8][8];
#pragma unroll
    for (int r = 0; r < 8; ++r)
#pragma unroll
        for (int j = 0; j < 8; ++j) acc[r][j] = 0.f;

    const float* wp = W + (size_t)obase * Cn;
#pragma unroll
    for (int it = 0; it < 4; ++it) {
        const int c = wv * 1024 + it * 256 + lane * 4;
        float4 w4[8], x4[8];
#pragma unroll
        for (int j = 0; j < 8; ++j) w4[j] = *(const float4*)(wp + (size_t)j * Cn + c);
#pragma unroll
        for (int r = 0; r < 8; ++r) x4[r] = *(const float4*)(xin + (size_t)r * Cn + c);
#pragma unroll
        for (int r = 0; r < 8; ++r)
#pragma unroll
            for (int j = 0; j < 8; ++j) {
                acc[r][j] = fmaf(x4[r].x, w4[j].x,
                            fmaf(x4[r].y, w4[j].y,
                            fmaf(x4[r].z, w4[j].z,
                            fmaf(x4[r].w, w4[j].w, acc[r][j]))));
            }
    }

    // Per-wave butterfly: every lane gets each sum; lane (r*8+j) keeps its own.
    const int lr = lane >> 3, lj = lane & 7;
    float mine = 0.f;
#pragma unroll
    for (int r = 0; r < 8; ++r)
#pragma unroll
        for (int j = 0; j < 8; ++j) {
            float v = acc[r][j];
#pragma unroll
            for (int off = 32; off; off >>= 1) v += __shfl_xor(v, off);
            if (lr == r && lj == j) mine = v;
        }

    __shared__ float red[4][64];
    red[wv][lane] = mine;
    __syncthreads();
    if (threadIdx.x < 64) {
        const float s = red[0][lane] + red[1][lane] + red[2][lane] + red[3][lane]
                      + bias[obase + lj];
        y[(size_t)lr * Cn + obase + lj] = s;
    }
}

// -------------------- flash-decode partial attention ------------------------
// grid (NCHUNK, H, B), 256 threads. Phase 1: 8 groups of 32 lanes compute
// QK dots (coalesced 1KB/wave rows) + shuffle reduce. Phase 2: coalesced V.
// cur substitution hoisted to a uniform per-block branch (only chunk 15 hits).
extern "C" __global__ __launch_bounds__(256) void attn_partial(
    const float* __restrict__ kp, const float* __restrict__ vp,
    const float* __restrict__ qn, const float* __restrict__ kn,
    const float* __restrict__ vn, const int* __restrict__ curp,
    float* __restrict__ pout, float* __restrict__ pml)
{
    const int chunk = blockIdx.x, h = blockIdx.y, b = blockIdx.z;
    const int tid = threadIdx.x;
    const int cur = *curp;

    __shared__ float  sc[CHUNK];
    __shared__ float  wred[8];
    __shared__ float4 red[8][32];

    const int l32 = tid & 31;
    const int g   = tid >> 5;           // 0..7
    const float4 q4   = *(const float4*)(qn + (size_t)b * Cn + h * Dn + l32 * 4);
    const float* newk = kn + (size_t)b * Cn + h * Dn;
    const float* newv = vn + (size_t)b * Cn + h * Dn;
    const int s0 = chunk * CHUNK;
    // base of this (b,h)'s rows within a page
    const float* kbase = kp + (((size_t)b * Hn + h) * PSn) * (size_t)Dn;
    const float* vbase = vp + (((size_t)b * Hn + h) * PSn) * (size_t)Dn;
    const size_t pgstride = (size_t)Bn * Hn * PSn * Dn;
    const bool has_cur = (cur >= s0) && (cur < s0 + CHUNK);

    // Phase 1: scores
    if (!has_cur) {
#pragma unroll 8
        for (int it = 0; it < CHUNK / 8; ++it) {
            const int sl = it * 8 + g;
            const int s  = s0 + sl;
            const float* krow = kbase + (size_t)(s >> 7) * pgstride + (size_t)(s & 127) * Dn;
            const float4 k4 = *(const float4*)(krow + l32 * 4);
            float d = fmaf(q4.x,k4.x, fmaf(q4.y,k4.y, fmaf(q4.z,k4.z, q4.w*k4.w)));
#pragma unroll
            for (int off = 16; off; off >>= 1) d += __shfl_xor(d, off);
            if (l32 == 0) sc[sl] = d * 0.08838834764831845f;
        }
    } else {
#pragma unroll 4
        for (int it = 0; it < CHUNK / 8; ++it) {
            const int sl = it * 8 + g;
            const int s  = s0 + sl;
            const float* krow = (s == cur) ? newk
                : kbase + (size_t)(s >> 7) * pgstride + (size_t)(s & 127) * Dn;
            const float4 k4 = *(const float4*)(krow + l32 * 4);
            float d = fmaf(q4.x,k4.x, fmaf(q4.y,k4.y, fmaf(q4.z,k4.z, q4.w*k4.w)));
#pragma unroll
            for (int off = 16; off; off >>= 1) d += __shfl_xor(d, off);
            if (l32 == 0) sc[sl] = d * 0.08838834764831845f;
        }
    }
    __syncthreads();

    // block softmax partial (m, l)
    float m = sc[tid];
#pragma unroll
    for (int off = 32; off; off >>= 1) m = fmaxf(m, __shfl_xor(m, off));
    if ((tid & 63) == 0) wred[tid >> 6] = m;
    __syncthreads();
    m = fmaxf(fmaxf(wred[0], wred[1]), fmaxf(wred[2], wred[3]));
    const float p = __expf(sc[tid] - m);
    sc[tid] = p;
    float l = p;
#pragma unroll
    for (int off = 32; off; off >>= 1) l += __shfl_xor(l, off);
    if ((tid & 63) == 0) wred[4 + (tid >> 6)] = l;
    __syncthreads();
    const float lsum = wred[4] + wred[5] + wred[6] + wred[7];

    // Phase 2: out_partial[d] = sum_s p[s] * v[s,d]
    const int d4 = tid & 31;
    const int sg = tid >> 5;
    float4 acc = make_float4(0.f, 0.f, 0.f, 0.f);
    if (!has_cur) {
#pragma unroll 4
        for (int it = 0; it < 32; ++it) {
            const int sl = it * 8 + sg;
            const int s  = s0 + sl;
            const float* vrow = vbase + (size_t)(s >> 7) * pgstride + (size_t)(s & 127) * Dn;
            const float4 v4 = *(const float4*)(vrow + d4 * 4);
            const float pw = sc[sl];
            acc.x = fmaf(pw, v4.x, acc.x);
            acc.y = fmaf(pw, v4.y, acc.y);
            acc.z = fmaf(pw, v4.z, acc.z);
            acc.w = fmaf(pw, v4.w, acc.w);
        }
    } else {
#pragma unroll 2
        for (int it = 0; it < 32; ++it) {
            const int sl = it * 8 + sg;
            const int s  = s0 + sl;
            const float* vrow = (s == cur) ? newv
                : vbase + (size_t)(s >> 7) * pgstride + (size_t)(s & 127) * Dn;
            const float4 v4 = *(const float4*)(vrow + d4 * 4);
            const float pw = sc[sl];
            acc.x = fmaf(pw, v4.x, acc.x);
            acc.y = fmaf(pw, v4.y, acc.y);
            acc.z = fmaf(pw, v4.z, acc.z);
            acc.w = fmaf(pw, v4.w, acc.w);
        }
    }
    red[sg][d4] = acc;
    __syncthreads();
    const int head = b * Hn + h;
    if (tid < 32) {
        float4 o = make_float4(0.f, 0.f, 0.f, 0.f);
#pragma unroll
        for (int i = 0; i < 8; ++i) {
            const float4 t = red[i][tid];
            o.x += t.x; o.y += t.y; o.z += t.z; o.w += t.w;
        }
        float* dst = pout + ((size_t)(head * NCHUNK + chunk)) * Dn + tid * 4;
        *(float4*)dst = o;
    }
    if (tid == 0) {
        pml[(head * NCHUNK + chunk) * 2 + 0] = m;
        pml[(head * NCHUNK + chunk) * 2 + 1] = lsum;
    }
}

// -------------------- combine partials --------------------------------------
extern "C" __global__ __launch_bounds__(128) void attn_combine(
    const float* __restrict__ pout, const float* __restrict__ pml,
    float* __restrict__ aout)
{
    const int head = blockIdx.x;   // 0..255 = b*H + h
    const int tid  = threadIdx.x;  // 0..127 = d
    __shared__ float ml[NCHUNK * 2];
    if (tid < NCHUNK * 2) ml[tid] = pml[head * NCHUNK * 2 + tid];
    __syncthreads();
    float mstar = -1e30f;
#pragma unroll
    for (int i = 0; i < NCHUNK; ++i) mstar = fmaxf(mstar, ml[2 * i]);
    float L = 0.f, acc = 0.f;
#pragma unroll
    for (int i = 0; i < NCHUNK; ++i) {
        const float w = __expf(ml[2 * i] - mstar);
        L   += ml[2 * i + 1] * w;
        acc += w * pout[((size_t)head * NCHUNK + i) * Dn + tid];
    }
    aout[(size_t)head * Dn + tid] = acc / L;
}

// -------------------- launch -------------------------------------------------
extern "C" void kernel_launch(void* const* d_in, const int* in_sizes, int n_in,
                              void* d_out, int out_size, void* d_ws, size_t ws_size,
                              hipStream_t stream)
{
    const float* x  = (const float*)d_in[0];
    const float* kp = (const float*)d_in[1];
    const float* vp = (const float*)d_in[2];
    const float* Wq = (const float*)d_in[3];
    const float* bq = (const float*)d_in[4];
    const float* Wk = (const float*)d_in[5];
    const float* bk = (const float*)d_in[6];
    const float* Wv = (const float*)d_in[7];
    const float* bv = (const float*)d_in[8];
    const float* Wo = (const float*)d_in[9];
    const float* bo = (const float*)d_in[10];
    const int* curp = (const int*)d_in[11];

    // ws layout (floats): q | k_new | v_new | pout | pml | attn_out  (~2.6 MB)
    float* ws   = (float*)d_ws;
    float* q    = ws;               // 32768
    float* kn   = ws + 32768;       // 32768
    float* vn   = ws + 65536;       // 32768
    float* pout = ws + 98304;       // 256*16*128 = 524288
    float* pml  = ws + 622592;      // 256*16*2   = 8192
    float* aout = ws + 630784;      // 32768
    float* dout = (float*)d_out;

    gemv8<<<dim3(512, 3), 256, 0, stream>>>(x, Wq, bq, Wk, bk, Wv, bv, q);
    attn_partial<<<dim3(NCHUNK, Hn, Bn), 256, 0, stream>>>(kp, vp, q, kn, vn, curp, pout, pml);
    attn_combine<<<256, 128, 0, stream>>>(pout, pml, aout);
    gemv8<<<dim3(512, 1), 256, 0, stream>>>(aout, Wo, bo, Wo, bo, Wo, bo, dout);
}